// Round 14
// baseline (198.648 us; speedup 1.0000x reference)
//
#include <hip/hip_runtime.h>

// Conv2d + BN int8 quantized, MI355X gfx950. Inputs fp32, output fp32.
// R19 = R18 with the epilogue typo fixed (acc[..][u][r], was missing [r]).
// R18 theory: R17's conv is LDS-port-bound (~45% of cyc): B frags depend only
// on lane, so all 8 waves read IDENTICAL b128s (8x redundancy). Re-split:
// wave = (ogh, uh): 64 o (og pair) x 32 ow (u half) per wave.
//   - B redundancy 8x -> 4x: LDS port 48K -> 24K cyc/CU
//   - A redundancy 1x -> 2x: L2 ~27 TB/s < 34.5 ceiling, latency hidden by pp
//   - same math/acc; B col = uh*32+u*16+l16+kw (phase invariant mod 8);
//     A consume formula untouched -> pure re-partition, correct by construction
//   - regs: acc32 + A-pp32 + B-pp16 + addr ~ 95 < 128 @ bounds(512,4)
// Host falls back to the proven R5 fused kernel if ws_size is too small.

#define BATCH 32
#define CIN   128
#define HH    56
#define WW    56
#define OCH   256

typedef __attribute__((ext_vector_type(4))) int int4v;

#define QX_BYTES (32 * 56 * 56 * 128)           // 12,845,056  qxp[b][h][w][c]
#define QW_BYTES (256 * 1152)                   // 294,912 (fragment-packed)
#define WS_NEEDED (QX_BYTES + QW_BYTES + 1024)

__device__ __forceinline__ void gload_lds16(const void* g, void* l) {
  __builtin_amdgcn_global_load_lds(
      (const __attribute__((address_space(1))) unsigned int*)g,
      (__attribute__((address_space(3))) unsigned int*)l, 16, 0, 0);
}

// ---------------- kernel 1: weight quantization + fragment pack ------------
// One block per output channel o. A-fragment layout for 16x16x64 i8 (R16):
//   int4v at qwf + og*36864 + ((r*2+c02)*2+t)*1024 + (quad*16+l16)*16
//   (= lane*16, HW lane order): byte e holds channel c02*64+quad*16+e of
//   o = og*32+t*16+l16 at tap r = kh*3+kw. Wave chunk per (r,c02,t) = 1KB.
__global__ __launch_bounds__(256) void quant_w_kernel(
    const float* __restrict__ w, const float* __restrict__ sxp,
    char* __restrict__ qwf, float* __restrict__ alpha) {
  __shared__ float wf[1152];
  __shared__ float red[256];
  const int o = blockIdx.x;
  const int tid = threadIdx.x;
  const float* wrow = w + (size_t)o * 1152;
  float m = 0.f;
  for (int i = tid; i < 288; i += 256) {
    const float4 v = ((const float4*)wrow)[i];
    ((float4*)wf)[i] = v;
    m = fmaxf(m, fmaxf(fmaxf(fabsf(v.x), fabsf(v.y)),
                       fmaxf(fabsf(v.z), fabsf(v.w))));
  }
  red[tid] = m;
  __syncthreads();
  for (int s = 128; s > 0; s >>= 1) {
    if (tid < s) red[tid] = fmaxf(red[tid], red[tid + s]);
    __syncthreads();
  }
  const float sc = red[0] / 127.0f;   // max/QMAX, fp32, matches reference
  if (tid == 0) alpha[o] = sc * sxp[0];
  if (tid < 72) {   // r = tid/8, c02 = (tid>>2)&1, quad = tid&3
    const int r = tid >> 3, c02 = (tid >> 2) & 1, quad = tid & 3;
    const int og = o >> 5, t = (o >> 4) & 1, l16 = o & 15;
    int4v pk;
#pragma unroll
    for (int d = 0; d < 4; ++d) {
      unsigned int p = 0;
#pragma unroll
      for (int k = 0; k < 4; ++k) {
        const int c = c02 * 64 + quad * 16 + d * 4 + k;
        const int q =
            (int)fminf(127.f, fmaxf(-127.f, rintf(wf[c * 9 + r] / sc)));
        p |= ((unsigned int)(q & 255)) << (8 * k);
      }
      pk[d] = (int)p;
    }
    *(int4v*)(qwf + (size_t)og * 36864 + ((r * 2 + c02) * 2 + t) * 1024 +
              (quad * 16 + l16) * 16) = pk;   // HW lane order (R16 fix)
  }
}

// ---------------- kernel 2: x quantization -> swizzled im2col rows ---------
// qxp byte ((b*56+h)*56 + w)*128 + j holds q(x[b][ j^(((w+1)&7)<<4) ][h][w]).
__global__ __launch_bounds__(256) void quant_x_kernel(
    const float* __restrict__ x, const float* __restrict__ sxp,
    unsigned int* __restrict__ qxp) {
  __shared__ char ldsA[128 * 60];   // [c][w] quantized bytes, stride 60
  const int row = blockIdx.x;       // b*56 + h
  const int b = row / 56, h = row % 56;
  const float sx = sxp[0];
  for (int i = threadIdx.x; i < 1792; i += 256) {
    const int c = i / 14, f = i % 14;
    const float4 v =
        *(const float4*)(x + (((size_t)b * 128 + c) * 56 + h) * 56 + 4 * f);
    unsigned int pk;
    pk  = (unsigned int)((int)fminf(127.f, fmaxf(-127.f, rintf(v.x / sx))) & 255);
    pk |= ((unsigned int)((int)fminf(127.f, fmaxf(-127.f, rintf(v.y / sx))) & 255)) << 8;
    pk |= ((unsigned int)((int)fminf(127.f, fmaxf(-127.f, rintf(v.z / sx))) & 255)) << 16;
    pk |= ((unsigned int)((int)fminf(127.f, fmaxf(-127.f, rintf(v.w / sx))) & 255)) << 24;
    *(unsigned int*)(ldsA + c * 60 + 4 * f) = pk;
  }
  __syncthreads();
  unsigned int* orow = qxp + (size_t)row * 56 * 32;
  for (int i = threadIdx.x; i < 1792; i += 256) {
    const int w = i >> 5, jd = i & 31;
    // byte p of row w holds channel p ^ (((w+1)&7)<<4); dword-level: ph<<2
    const int c0 = (jd ^ (((w + 1) & 7) << 2)) << 2;  // channel base (4-run)
    unsigned int pk = 0;
#pragma unroll
    for (int k = 0; k < 4; ++k)
      pk |= ((unsigned int)(unsigned char)ldsA[(c0 + k) * 60 + w]) << (8 * k);
    orow[i] = pk;
  }
}

// ---------------- kernel 3: conv (16x16x64 i8, wave = 64o x 32ow) ----------
#define XSLAB 8448                  // 66 cols * 128B, contiguous (no pad)

__global__ __launch_bounds__(512, 4) void conv_kernel(
    const char* __restrict__ qxp, const char* __restrict__ qwf,
    const float* __restrict__ alpha, const float* __restrict__ bias,
    float* __restrict__ out) {
  __shared__ __attribute__((aligned(16))) char Xs8[3 * XSLAB];  // 25,344 B

  // chunked XCD swizzle: 1792 = 8*224; XCD (id&7) owns bi in [xcd*224,+224)
  const int id = blockIdx.x;        // 0..1791
  const int xcd = id & 7;
  const int bi = xcd * 224 + (id >> 3);
  const int b  = bi / 56;
  const int oh = bi % 56;
  const int tid = threadIdx.x;      // 0..511
  const int wave = tid >> 6, lane = tid & 63;
  const int l16 = lane & 15, quad = lane >> 4;
  const int ogh = wave >> 1;        // 0..3 : o-base ogh*64 (og pair)
  const int uh  = wave & 1;         // 0..1 : ow-base uh*32

  // A bases for the wave's two og values; per-lane int4v (16B).
  const int4v* wbA0 =
      (const int4v*)(qwf + (size_t)(ogh * 2 + 0) * 36864) + lane;
  const int4v* wbA1 =
      (const int4v*)(qwf + (size_t)(ogh * 2 + 1) * 36864) + lane;

  // A prologue for substep 0 (independent of LDS; issues early)
  int4v ap[2][4];                   // [buf][ogl*2+t]
#pragma unroll
  for (int t = 0; t < 2; ++t) {
    ap[0][t]     = wbA0[(size_t)t * 64];       // ss=0: ((0)*2+t)*64
    ap[0][2 + t] = wbA1[(size_t)t * 64];
  }

  // ---- stage 3 input rows once for ALL 256 o (512 threads) ----
  for (int kh = 0; kh < 3; ++kh) {
    const int ih = oh - 1 + kh;
    char* slab = Xs8 + kh * XSLAB;
    if (ih >= 0 && ih < HH) {
      const char* src = qxp + ((size_t)b * 56 + ih) * 7168;
      if (tid < 448) gload_lds16(src + tid * 16, slab + 128 + tid * 16);
      for (int i = tid; i < 320; i += 512) {              // zero cols 0,57..65
        const int cg = i >> 5, dw = i & 31;
        const int col = (cg == 0) ? 0 : 56 + cg;
        ((unsigned int*)slab)[col * 32 + dw] = 0u;
      }
    } else {
      for (int i = tid; i < 2112; i += 512) ((unsigned int*)slab)[i] = 0u;
    }
  }

  int4v acc[4][2];                  // [ogl*2+t][u]
#pragma unroll
  for (int g = 0; g < 4; ++g)
#pragma unroll
    for (int u = 0; u < 2; ++u) acc[g][u] = (int4v){0, 0, 0, 0};

  __syncthreads();   // drains vmcnt (global_load_lds + ap[0]) + lgkm

  // ---- K-loop: 18 substeps, A-pp (4 frags) + B-pp (2 frags) per substep ---
  int4v bops[2][2];
  {
    const int ph0 = (l16 & 7) << 4;         // ss=0: kh=0, kw=0, c02=0
    const int boff0 = (quad * 16) ^ ph0;
#pragma unroll
    for (int u = 0; u < 2; ++u)
      bops[0][u] =
          *(const int4v*)(Xs8 + (uh * 32 + u * 16 + l16) * 128 + boff0);
  }
#pragma unroll
  for (int ss = 0; ss < 18; ++ss) {
    // prefetch next substep's B (2x ds_read_b128) and A (4x L2 dwordx4)
    if (ss + 1 < 18) {
      const int gn = (ss + 1) >> 1, cn = (ss + 1) & 1;
      const int khn = gn / 3, kwn = gn % 3;
      const char* Xkn = Xs8 + khn * XSLAB;
      const int phn = ((l16 + kwn) & 7) << 4;
      const int boffn = (cn * 64 + quad * 16) ^ phn;
#pragma unroll
      for (int u = 0; u < 2; ++u)
        bops[(ss + 1) & 1][u] = *(const int4v*)(
            Xkn + (uh * 32 + u * 16 + l16 + kwn) * 128 + boffn);
#pragma unroll
      for (int t = 0; t < 2; ++t) {
        ap[(ss + 1) & 1][t]     = wbA0[(size_t)((ss + 1) * 2 + t) * 64];
        ap[(ss + 1) & 1][2 + t] = wbA1[(size_t)((ss + 1) * 2 + t) * 64];
      }
    }
#pragma unroll
    for (int gt = 0; gt < 4; ++gt)
#pragma unroll
      for (int u = 0; u < 2; ++u)
        acc[gt][u] = __builtin_amdgcn_mfma_i32_16x16x64_i8(
            ap[ss & 1][gt], bops[ss & 1][u], acc[gt][u], 0, 0, 0);
  }

  // C/D layout (HW-verified, proven since R12): row = quad*4+r, col = l16
#pragma unroll
  for (int ogl = 0; ogl < 2; ++ogl) {
#pragma unroll
    for (int t = 0; t < 2; ++t) {
#pragma unroll
      for (int r = 0; r < 4; ++r) {
        const int o = ogh * 64 + ogl * 32 + t * 16 + quad * 4 + r;
        const float al = alpha[o], bz = bias[o];
        float* orow = out + (((size_t)b * OCH + o) * HH + oh) * WW;
#pragma unroll
        for (int u = 0; u < 2; ++u) {
          const int ow = uh * 32 + u * 16 + l16;
          if (ow < WW) orow[ow] = (float)acc[ogl * 2 + t][u][r] * al + bz;
        }
      }
    }
  }
}

// ---------------- fallback: R5's proven fused kernel (ws-free) -------------
#define FAS_ROW 392
#define FXS_ROW 136
#define FLDS_XS (128 * FAS_ROW)
#define FLDS_SC (FLDS_XS + 66 * FXS_ROW)
#define FLDS_AL (FLDS_SC + 512)
#define FLDS_BI (FLDS_AL + 512)
#define FLDS_RED (FLDS_BI + 512)
#define FLDS_TOT (FLDS_RED + 1024)

__global__ __launch_bounds__(256) void conv_fused_kernel(
    const float* __restrict__ x, const float* __restrict__ w,
    const float* __restrict__ bias, const float* __restrict__ sxp,
    float* __restrict__ out) {
  __shared__ __attribute__((aligned(16))) char lds[FLDS_TOT];
  char* As8 = lds;
  char* Xs8 = lds + FLDS_XS;
  float* scaleS = (float*)(lds + FLDS_SC);
  float* alphaS = (float*)(lds + FLDS_AL);
  float* biasS  = (float*)(lds + FLDS_BI);
  float* red    = (float*)(lds + FLDS_RED);

  const int bi = blockIdx.x;
  const int b  = bi / 56;
  const int oh = bi % 56;
  const int o0 = blockIdx.y * 128;
  const int tid = threadIdx.x;
  const int wave = tid >> 6, lane = tid & 63;
  const int l16 = lane & 15, quad = lane >> 4;
  const float sx = sxp[0];

  typedef __attribute__((ext_vector_type(4))) int int4vf;
  int m_r[4], n_r[4];
  {
    int4vf zz = {0, 0, 0, 0};
    long a1 = 0, b1 = 0, a2 = 0, b2 = 0;
    if (quad == 0) { a1 = 1L; b1 = (long)(l16 + 1); a2 = (long)(l16 + 1); b2 = 1L; }
    int4vf d1 = __builtin_amdgcn_mfma_i32_16x16x32_i8(a1, b1, zz, 0, 0, 0);
    int4vf d2 = __builtin_amdgcn_mfma_i32_16x16x32_i8(a2, b2, zz, 0, 0, 0);
#pragma unroll
    for (int r = 0; r < 4; ++r) { n_r[r] = (d1[r] - 1) & 15; m_r[r] = (d2[r] - 1) & 15; }
  }
  {
    const int o = tid >> 1, half = tid & 1;
    const float4* p = (const float4*)(w + (size_t)(o0 + o) * 1152 + half * 576);
    float m = 0.f;
#pragma unroll 4
    for (int i = 0; i < 144; ++i) {
      const float4 v = p[i];
      m = fmaxf(m, fmaxf(fmaxf(fabsf(v.x), fabsf(v.y)), fmaxf(fabsf(v.z), fabsf(v.w))));
    }
    red[tid] = m;
  }
  __syncthreads();
  {
    const int o = tid >> 1;
    if ((tid & 1) == 0) {
      const float sc = fmaxf(red[2 * o], red[2 * o + 1]) / 127.0f;
      scaleS[o] = sc; alphaS[o] = sc * sx; biasS[o] = bias[o0 + o];
    }
  }
  int4vf acc[2][4];
#pragma unroll
  for (int t = 0; t < 2; ++t)
#pragma unroll
    for (int u = 0; u < 4; ++u) acc[t][u] = (int4vf){0, 0, 0, 0};

  for (int kh = 0; kh < 3; ++kh) {
    const int ih = oh - 1 + kh;
    const bool row_ok = (ih >= 0) && (ih < HH);
    __syncthreads();
    for (int idx = tid; idx < 66 * 128; idx += 256) {
      const int col = idx % 66, c = idx / 66, iw = col - 1;
      int q = 0;
      if (row_ok && iw >= 0 && iw < WW) {
        const float xv = x[(((size_t)b * CIN + c) * HH + ih) * WW + iw];
        q = (int)fminf(127.f, fmaxf(-127.f, rintf(xv / sx)));
      }
      Xs8[col * FXS_ROW + c] = (char)q;
    }
    for (int idx = tid; idx < 16384; idx += 256) {
      const int c = idx & 127, o = idx >> 7;
      const float s = scaleS[o];
      const float* wp = w + (size_t)(o0 + o) * 1152 + c * 9 + kh * 3;
#pragma unroll
      for (int kw = 0; kw < 3; ++kw) {
        const int q = (int)fminf(127.f, fmaxf(-127.f, rintf(wp[kw] / s)));
        As8[o * FAS_ROW + kw * 128 + c] = (char)q;
      }
    }
    __syncthreads();
    const int obase = wave * 32;
#pragma unroll
    for (int kw = 0; kw < 3; ++kw) {
#pragma unroll
      for (int c0 = 0; c0 < 128; c0 += 32) {
        long aop[2], bop[4];
#pragma unroll
        for (int t = 0; t < 2; ++t)
          aop[t] = *(const long*)(As8 + (obase + t * 16 + l16) * FAS_ROW + kw * 128 + c0 + quad * 8);
#pragma unroll
        for (int u = 0; u < 4; ++u)
          bop[u] = *(const long*)(Xs8 + (u * 16 + l16 + kw) * FXS_ROW + c0 + quad * 8);
#pragma unroll
        for (int t = 0; t < 2; ++t)
#pragma unroll
          for (int u = 0; u < 4; ++u)
            acc[t][u] = __builtin_amdgcn_mfma_i32_16x16x32_i8(aop[t], bop[u], acc[t][u], 0, 0, 0);
      }
    }
  }
#pragma unroll
  for (int t = 0; t < 2; ++t) {
#pragma unroll
    for (int u = 0; u < 4; ++u) {
#pragma unroll
      for (int r = 0; r < 4; ++r) {
        const int ol = wave * 32 + t * 16 + m_r[r];
        const int ow = u * 16 + n_r[r];
        if (ow < WW)
          out[(((size_t)b * OCH + o0 + ol) * HH + oh) * WW + ow] =
              (float)acc[t][u][r] * alphaS[ol] + biasS[ol];
      }
    }
  }
}

extern "C" void kernel_launch(void* const* d_in, const int* in_sizes, int n_in,
                              void* d_out, int out_size, void* d_ws, size_t ws_size,
                              hipStream_t stream) {
  const float *x = nullptr, *w = nullptr, *bias = nullptr, *sx = nullptr;
  for (int i = 0; i < n_in; ++i) {
    const int s = in_sizes[i];
    if (s == BATCH * CIN * HH * WW) x = (const float*)d_in[i];
    else if (s == OCH * CIN * 9)    w = (const float*)d_in[i];
    else if (s == OCH)              bias = (const float*)d_in[i];
    else if (s == 1)                sx = (const float*)d_in[i];
  }
  if (!x || !w || !bias || !sx) {
    x = (const float*)d_in[0]; w = (const float*)d_in[1];
    bias = (const float*)d_in[2]; sx = (const float*)d_in[3];
  }
  float* out = (float*)d_out;

  if (ws_size >= (size_t)WS_NEEDED) {
    unsigned int* qxp = (unsigned int*)d_ws;
    char* qwf = (char*)d_ws + QX_BYTES;
    float* alpha = (float*)((char*)d_ws + QX_BYTES + QW_BYTES);
    quant_w_kernel<<<OCH, 256, 0, stream>>>(w, sx, qwf, alpha);
    quant_x_kernel<<<BATCH * HH, 256, 0, stream>>>(x, sx, qxp);
    conv_kernel<<<BATCH * HH, 512, 0, stream>>>(
        (const char*)qxp, qwf, alpha, bias, out);
  } else {
    conv_fused_kernel<<<dim3(BATCH * HH, 2), 256, 0, stream>>>(x, w, bias, sx, out);
  }
}

// Round 15
// 192.328 us; speedup vs baseline: 1.0329x; 1.0329x over previous
//
#include <hip/hip_runtime.h>

// Conv2d + BN int8 quantized, MI355X gfx950. Inputs fp32, output fp32.
// R20 = R17 (proven best, conv ~45us) with ONE change: launch_bounds(512,4)
// -> (512,8). R19 taught: (a) M=32/N=64 per wave is the balanced optimum
// (A-L2 ~13us, LDS ~18us, MFMA ~17us); R19's M=64/N=32 doubled A-L2 -> 63us.
// (b) compiler collapses ping-pongs to JIT loads (VGPR=44) -> regs are NOT
// the occupancy limit; the bounds(512,4) DECLARATION was (16 waves/CU cap).
// (512,8) allows 32 waves/CU (4 blocks x 25.3KB LDS = 101KB fits) to close
// the overlap gap (45us vs ~18us max-pipe floor). Spill signature to watch:
// WRITE >> 105MB.
// Host falls back to the proven R5 fused kernel if ws_size is too small.

#define BATCH 32
#define CIN   128
#define HH    56
#define WW    56
#define OCH   256

typedef __attribute__((ext_vector_type(4))) int int4v;

#define QX_BYTES (32 * 56 * 56 * 128)           // 12,845,056  qxp[b][h][w][c]
#define QW_BYTES (256 * 1152)                   // 294,912 (fragment-packed)
#define WS_NEEDED (QX_BYTES + QW_BYTES + 1024)

__device__ __forceinline__ void gload_lds16(const void* g, void* l) {
  __builtin_amdgcn_global_load_lds(
      (const __attribute__((address_space(1))) unsigned int*)g,
      (__attribute__((address_space(3))) unsigned int*)l, 16, 0, 0);
}

// ---------------- kernel 1: weight quantization + fragment pack ------------
// One block per output channel o. A-fragment layout for 16x16x64 i8 (R16):
//   int4v at qwf + og*36864 + ((r*2+c02)*2+t)*1024 + (quad*16+l16)*16
//   (= lane*16, HW lane order): byte e holds channel c02*64+quad*16+e of
//   o = og*32+t*16+l16 at tap r = kh*3+kw. Wave chunk per (r,c02,t) = 1KB.
__global__ __launch_bounds__(256) void quant_w_kernel(
    const float* __restrict__ w, const float* __restrict__ sxp,
    char* __restrict__ qwf, float* __restrict__ alpha) {
  __shared__ float wf[1152];
  __shared__ float red[256];
  const int o = blockIdx.x;
  const int tid = threadIdx.x;
  const float* wrow = w + (size_t)o * 1152;
  float m = 0.f;
  for (int i = tid; i < 288; i += 256) {
    const float4 v = ((const float4*)wrow)[i];
    ((float4*)wf)[i] = v;
    m = fmaxf(m, fmaxf(fmaxf(fabsf(v.x), fabsf(v.y)),
                       fmaxf(fabsf(v.z), fabsf(v.w))));
  }
  red[tid] = m;
  __syncthreads();
  for (int s = 128; s > 0; s >>= 1) {
    if (tid < s) red[tid] = fmaxf(red[tid], red[tid + s]);
    __syncthreads();
  }
  const float sc = red[0] / 127.0f;   // max/QMAX, fp32, matches reference
  if (tid == 0) alpha[o] = sc * sxp[0];
  if (tid < 72) {   // r = tid/8, c02 = (tid>>2)&1, quad = tid&3
    const int r = tid >> 3, c02 = (tid >> 2) & 1, quad = tid & 3;
    const int og = o >> 5, t = (o >> 4) & 1, l16 = o & 15;
    int4v pk;
#pragma unroll
    for (int d = 0; d < 4; ++d) {
      unsigned int p = 0;
#pragma unroll
      for (int k = 0; k < 4; ++k) {
        const int c = c02 * 64 + quad * 16 + d * 4 + k;
        const int q =
            (int)fminf(127.f, fmaxf(-127.f, rintf(wf[c * 9 + r] / sc)));
        p |= ((unsigned int)(q & 255)) << (8 * k);
      }
      pk[d] = (int)p;
    }
    *(int4v*)(qwf + (size_t)og * 36864 + ((r * 2 + c02) * 2 + t) * 1024 +
              (quad * 16 + l16) * 16) = pk;   // HW lane order (R16 fix)
  }
}

// ---------------- kernel 2: x quantization -> swizzled im2col rows ---------
// qxp byte ((b*56+h)*56 + w)*128 + j holds q(x[b][ j^(((w+1)&7)<<4) ][h][w]).
__global__ __launch_bounds__(256) void quant_x_kernel(
    const float* __restrict__ x, const float* __restrict__ sxp,
    unsigned int* __restrict__ qxp) {
  __shared__ char ldsA[128 * 60];   // [c][w] quantized bytes, stride 60
  const int row = blockIdx.x;       // b*56 + h
  const int b = row / 56, h = row % 56;
  const float sx = sxp[0];
  for (int i = threadIdx.x; i < 1792; i += 256) {
    const int c = i / 14, f = i % 14;
    const float4 v =
        *(const float4*)(x + (((size_t)b * 128 + c) * 56 + h) * 56 + 4 * f);
    unsigned int pk;
    pk  = (unsigned int)((int)fminf(127.f, fmaxf(-127.f, rintf(v.x / sx))) & 255);
    pk |= ((unsigned int)((int)fminf(127.f, fmaxf(-127.f, rintf(v.y / sx))) & 255)) << 8;
    pk |= ((unsigned int)((int)fminf(127.f, fmaxf(-127.f, rintf(v.z / sx))) & 255)) << 16;
    pk |= ((unsigned int)((int)fminf(127.f, fmaxf(-127.f, rintf(v.w / sx))) & 255)) << 24;
    *(unsigned int*)(ldsA + c * 60 + 4 * f) = pk;
  }
  __syncthreads();
  unsigned int* orow = qxp + (size_t)row * 56 * 32;
  for (int i = threadIdx.x; i < 1792; i += 256) {
    const int w = i >> 5, jd = i & 31;
    // byte p of row w holds channel p ^ (((w+1)&7)<<4); dword-level: ph<<2
    const int c0 = (jd ^ (((w + 1) & 7) << 2)) << 2;  // channel base (4-run)
    unsigned int pk = 0;
#pragma unroll
    for (int k = 0; k < 4; ++k)
      pk |= ((unsigned int)(unsigned char)ldsA[(c0 + k) * 60 + w]) << (8 * k);
    orow[i] = pk;
  }
}

// ---------------- kernel 3: conv (16x16x64 i8, 8 waves, 256 o per block) ---
#define XSLAB 8448                  // 66 cols * 128B, contiguous (no pad)

__global__ __launch_bounds__(512, 8) void conv_kernel(
    const char* __restrict__ qxp, const char* __restrict__ qwf,
    const float* __restrict__ alpha, const float* __restrict__ bias,
    float* __restrict__ out) {
  __shared__ __attribute__((aligned(16))) char Xs8[3 * XSLAB];  // 25,344 B

  // chunked XCD swizzle: 1792 = 8*224; XCD (id&7) owns bi in [xcd*224,+224)
  const int id = blockIdx.x;        // 0..1791
  const int xcd = id & 7;
  const int bi = xcd * 224 + (id >> 3);
  const int b  = bi / 56;
  const int oh = bi % 56;
  const int tid = threadIdx.x;      // 0..511
  const int wave = tid >> 6, lane = tid & 63;   // wave = og, 0..7
  const int l16 = lane & 15, quad = lane >> 4;

  // A-operand base: per-lane int4v (16B); wave chunk per (r,c02,t) = 1KB.
  const int4v* wbA = (const int4v*)(qwf + (size_t)wave * 36864) + lane;
  int4v ap[2][2][2];                // [buf][c02][t]
#pragma unroll
  for (int c02 = 0; c02 < 2; ++c02)
#pragma unroll
    for (int t = 0; t < 2; ++t)
      ap[0][c02][t] = wbA[(size_t)(c02 * 2 + t) * 64];   // r = 0

  // ---- stage 3 input rows once for ALL 256 o (512 threads) ----
  for (int kh = 0; kh < 3; ++kh) {
    const int ih = oh - 1 + kh;
    char* slab = Xs8 + kh * XSLAB;
    if (ih >= 0 && ih < HH) {
      const char* src = qxp + ((size_t)b * 56 + ih) * 7168;
      if (tid < 448) gload_lds16(src + tid * 16, slab + 128 + tid * 16);
      for (int i = tid; i < 320; i += 512) {              // zero cols 0,57..65
        const int cg = i >> 5, dw = i & 31;
        const int col = (cg == 0) ? 0 : 56 + cg;
        ((unsigned int*)slab)[col * 32 + dw] = 0u;
      }
    } else {
      for (int i = tid; i < 2112; i += 512) ((unsigned int*)slab)[i] = 0u;
    }
  }

  int4v acc[2][4];
#pragma unroll
  for (int t = 0; t < 2; ++t)
#pragma unroll
    for (int u = 0; u < 4; ++u) acc[t][u] = (int4v){0, 0, 0, 0};

  __syncthreads();   // drains vmcnt (global_load_lds + ap[0]) + lgkm

  // ---- K-loop: 18 substeps (9 taps x 2 K64-chunks), B-pp, A-pp per tap ----
  int4v bops[2][4];
  {
    const int ph0 = (l16 & 7) << 4;         // g=0: kh=0, kw=0
    const int boff0 = (quad * 16) ^ ph0;    // c02=0
#pragma unroll
    for (int u = 0; u < 4; ++u)
      bops[0][u] = *(const int4v*)(Xs8 + (u * 16 + l16) * 128 + boff0);
  }
#pragma unroll
  for (int ss = 0; ss < 18; ++ss) {
    const int g = ss >> 1, c02 = ss & 1;
    // prefetch next substep's B fragments (static after unroll)
    if (ss + 1 < 18) {
      const int gn = (ss + 1) >> 1, cn = (ss + 1) & 1;
      const int khn = gn / 3, kwn = gn % 3;
      const char* Xkn = Xs8 + khn * XSLAB;
      const int phn = ((l16 + kwn) & 7) << 4;
      const int boffn = (cn * 64 + quad * 16) ^ phn;
#pragma unroll
      for (int u = 0; u < 4; ++u)
        bops[(ss + 1) & 1][u] =
            *(const int4v*)(Xkn + (u * 16 + l16 + kwn) * 128 + boffn);
    }
    // prefetch next tap's A fragments (once per g)
    if (c02 == 0 && g < 8) {
#pragma unroll
      for (int cc = 0; cc < 2; ++cc)
#pragma unroll
        for (int t = 0; t < 2; ++t)
          ap[(g + 1) & 1][cc][t] =
              wbA[(size_t)(((g + 1) * 2 + cc) * 2 + t) * 64];
    }
#pragma unroll
    for (int u = 0; u < 4; ++u) {
      acc[0][u] = __builtin_amdgcn_mfma_i32_16x16x64_i8(
          ap[g & 1][c02][0], bops[ss & 1][u], acc[0][u], 0, 0, 0);
      acc[1][u] = __builtin_amdgcn_mfma_i32_16x16x64_i8(
          ap[g & 1][c02][1], bops[ss & 1][u], acc[1][u], 0, 0, 0);
    }
  }

  // C/D layout (HW-verified, proven since R12): row = quad*4+r, col = l16
#pragma unroll
  for (int t = 0; t < 2; ++t) {
#pragma unroll
    for (int r = 0; r < 4; ++r) {
      const int o = wave * 32 + t * 16 + quad * 4 + r;
      const float al = alpha[o], bz = bias[o];
      float* orow = out + (((size_t)b * OCH + o) * HH + oh) * WW;
#pragma unroll
      for (int u = 0; u < 4; ++u) {
        const int ow = u * 16 + l16;
        if (ow < WW) orow[ow] = (float)acc[t][u][r] * al + bz;
      }
    }
  }
}

// ---------------- fallback: R5's proven fused kernel (ws-free) -------------
#define FAS_ROW 392
#define FXS_ROW 136
#define FLDS_XS (128 * FAS_ROW)
#define FLDS_SC (FLDS_XS + 66 * FXS_ROW)
#define FLDS_AL (FLDS_SC + 512)
#define FLDS_BI (FLDS_AL + 512)
#define FLDS_RED (FLDS_BI + 512)
#define FLDS_TOT (FLDS_RED + 1024)

__global__ __launch_bounds__(256) void conv_fused_kernel(
    const float* __restrict__ x, const float* __restrict__ w,
    const float* __restrict__ bias, const float* __restrict__ sxp,
    float* __restrict__ out) {
  __shared__ __attribute__((aligned(16))) char lds[FLDS_TOT];
  char* As8 = lds;
  char* Xs8 = lds + FLDS_XS;
  float* scaleS = (float*)(lds + FLDS_SC);
  float* alphaS = (float*)(lds + FLDS_AL);
  float* biasS  = (float*)(lds + FLDS_BI);
  float* red    = (float*)(lds + FLDS_RED);

  const int bi = blockIdx.x;
  const int b  = bi / 56;
  const int oh = bi % 56;
  const int o0 = blockIdx.y * 128;
  const int tid = threadIdx.x;
  const int wave = tid >> 6, lane = tid & 63;
  const int l16 = lane & 15, quad = lane >> 4;
  const float sx = sxp[0];

  typedef __attribute__((ext_vector_type(4))) int int4vf;
  int m_r[4], n_r[4];
  {
    int4vf zz = {0, 0, 0, 0};
    long a1 = 0, b1 = 0, a2 = 0, b2 = 0;
    if (quad == 0) { a1 = 1L; b1 = (long)(l16 + 1); a2 = (long)(l16 + 1); b2 = 1L; }
    int4vf d1 = __builtin_amdgcn_mfma_i32_16x16x32_i8(a1, b1, zz, 0, 0, 0);
    int4vf d2 = __builtin_amdgcn_mfma_i32_16x16x32_i8(a2, b2, zz, 0, 0, 0);
#pragma unroll
    for (int r = 0; r < 4; ++r) { n_r[r] = (d1[r] - 1) & 15; m_r[r] = (d2[r] - 1) & 15; }
  }
  {
    const int o = tid >> 1, half = tid & 1;
    const float4* p = (const float4*)(w + (size_t)(o0 + o) * 1152 + half * 576);
    float m = 0.f;
#pragma unroll 4
    for (int i = 0; i < 144; ++i) {
      const float4 v = p[i];
      m = fmaxf(m, fmaxf(fmaxf(fabsf(v.x), fabsf(v.y)), fmaxf(fabsf(v.z), fabsf(v.w))));
    }
    red[tid] = m;
  }
  __syncthreads();
  {
    const int o = tid >> 1;
    if ((tid & 1) == 0) {
      const float sc = fmaxf(red[2 * o], red[2 * o + 1]) / 127.0f;
      scaleS[o] = sc; alphaS[o] = sc * sx; biasS[o] = bias[o0 + o];
    }
  }
  int4vf acc[2][4];
#pragma unroll
  for (int t = 0; t < 2; ++t)
#pragma unroll
    for (int u = 0; u < 4; ++u) acc[t][u] = (int4vf){0, 0, 0, 0};

  for (int kh = 0; kh < 3; ++kh) {
    const int ih = oh - 1 + kh;
    const bool row_ok = (ih >= 0) && (ih < HH);
    __syncthreads();
    for (int idx = tid; idx < 66 * 128; idx += 256) {
      const int col = idx % 66, c = idx / 66, iw = col - 1;
      int q = 0;
      if (row_ok && iw >= 0 && iw < WW) {
        const float xv = x[(((size_t)b * CIN + c) * HH + ih) * WW + iw];
        q = (int)fminf(127.f, fmaxf(-127.f, rintf(xv / sx)));
      }
      Xs8[col * FXS_ROW + c] = (char)q;
    }
    for (int idx = tid; idx < 16384; idx += 256) {
      const int c = idx & 127, o = idx >> 7;
      const float s = scaleS[o];
      const float* wp = w + (size_t)(o0 + o) * 1152 + c * 9 + kh * 3;
#pragma unroll
      for (int kw = 0; kw < 3; ++kw) {
        const int q = (int)fminf(127.f, fmaxf(-127.f, rintf(wp[kw] / s)));
        As8[o * FAS_ROW + kw * 128 + c] = (char)q;
      }
    }
    __syncthreads();
    const int obase = wave * 32;
#pragma unroll
    for (int kw = 0; kw < 3; ++kw) {
#pragma unroll
      for (int c0 = 0; c0 < 128; c0 += 32) {
        long aop[2], bop[4];
#pragma unroll
        for (int t = 0; t < 2; ++t)
          aop[t] = *(const long*)(As8 + (obase + t * 16 + l16) * FAS_ROW + kw * 128 + c0 + quad * 8);
#pragma unroll
        for (int u = 0; u < 4; ++u)
          bop[u] = *(const long*)(Xs8 + (u * 16 + l16 + kw) * FXS_ROW + c0 + quad * 8);
#pragma unroll
        for (int t = 0; t < 2; ++t)
#pragma unroll
          for (int u = 0; u < 4; ++u)
            acc[t][u] = __builtin_amdgcn_mfma_i32_16x16x32_i8(aop[t], bop[u], acc[t][u], 0, 0, 0);
      }
    }
  }
#pragma unroll
  for (int t = 0; t < 2; ++t) {
#pragma unroll
    for (int u = 0; u < 4; ++u) {
#pragma unroll
      for (int r = 0; r < 4; ++r) {
        const int ol = wave * 32 + t * 16 + m_r[r];
        const int ow = u * 16 + n_r[r];
        if (ow < WW)
          out[(((size_t)b * OCH + o0 + ol) * HH + oh) * WW + ow] =
              (float)acc[t][u][r] * alphaS[ol] + biasS[ol];
      }
    }
  }
}

extern "C" void kernel_launch(void* const* d_in, const int* in_sizes, int n_in,
                              void* d_out, int out_size, void* d_ws, size_t ws_size,
                              hipStream_t stream) {
  const float *x = nullptr, *w = nullptr, *bias = nullptr, *sx = nullptr;
  for (int i = 0; i < n_in; ++i) {
    const int s = in_sizes[i];
    if (s == BATCH * CIN * HH * WW) x = (const float*)d_in[i];
    else if (s == OCH * CIN * 9)    w = (const float*)d_in[i];
    else if (s == OCH)              bias = (const float*)d_in[i];
    else if (s == 1)                sx = (const float*)d_in[i];
  }
  if (!x || !w || !bias || !sx) {
    x = (const float*)d_in[0]; w = (const float*)d_in[1];
    bias = (const float*)d_in[2]; sx = (const float*)d_in[3];
  }
  float* out = (float*)d_out;

  if (ws_size >= (size_t)WS_NEEDED) {
    unsigned int* qxp = (unsigned int*)d_ws;
    char* qwf = (char*)d_ws + QX_BYTES;
    float* alpha = (float*)((char*)d_ws + QX_BYTES + QW_BYTES);
    quant_w_kernel<<<OCH, 256, 0, stream>>>(w, sx, qwf, alpha);
    quant_x_kernel<<<BATCH * HH, 256, 0, stream>>>(x, sx, qxp);
    conv_kernel<<<BATCH * HH, 512, 0, stream>>>(
        (const char*)qxp, qwf, alpha, bias, out);
  } else {
    conv_fused_kernel<<<dim3(BATCH * HH, 2), 256, 0, stream>>>(x, w, bias, sx, out);
  }
}

// Round 16
// 184.476 us; speedup vs baseline: 1.0768x; 1.0426x over previous
//
#include <hip/hip_runtime.h>

// Conv2d + BN int8 quantized, MI355X gfx950. Inputs fp32, output fp32.
// R21 = R17 restored verbatim (proven best: 181.3us total, conv ~45us).
// R17-R20 established R17 as a measured local optimum:
//   - wave split M=32o/N=64ow balances A-L2 ~13us / LDS ~18us / MFMA ~17us
//     (R19's M=64/N=32 doubled A-L2 -> conv 63us)
//   - bounds(512,4): 16 waves/CU WITH full prefetch depth beats (512,8)'s
//     32 waves with 64-reg cap (prefetch demoted to JIT -> conv ~56us, R20)
//   - 8-wave staging-shared block (3 slabs serve all 256 o), 16x16x64 i8,
//     3bit/16B qxp swizzle, chunked XCD swizzle 1792=8*224.
// Host falls back to the proven R5 fused kernel if ws_size is too small.

#define BATCH 32
#define CIN   128
#define HH    56
#define WW    56
#define OCH   256

typedef __attribute__((ext_vector_type(4))) int int4v;

#define QX_BYTES (32 * 56 * 56 * 128)           // 12,845,056  qxp[b][h][w][c]
#define QW_BYTES (256 * 1152)                   // 294,912 (fragment-packed)
#define WS_NEEDED (QX_BYTES + QW_BYTES + 1024)

__device__ __forceinline__ void gload_lds16(const void* g, void* l) {
  __builtin_amdgcn_global_load_lds(
      (const __attribute__((address_space(1))) unsigned int*)g,
      (__attribute__((address_space(3))) unsigned int*)l, 16, 0, 0);
}

// ---------------- kernel 1: weight quantization + fragment pack ------------
// One block per output channel o. A-fragment layout for 16x16x64 i8 (R16):
//   int4v at qwf + og*36864 + ((r*2+c02)*2+t)*1024 + (quad*16+l16)*16
//   (= lane*16, HW lane order): byte e holds channel c02*64+quad*16+e of
//   o = og*32+t*16+l16 at tap r = kh*3+kw. Wave chunk per (r,c02,t) = 1KB.
__global__ __launch_bounds__(256) void quant_w_kernel(
    const float* __restrict__ w, const float* __restrict__ sxp,
    char* __restrict__ qwf, float* __restrict__ alpha) {
  __shared__ float wf[1152];
  __shared__ float red[256];
  const int o = blockIdx.x;
  const int tid = threadIdx.x;
  const float* wrow = w + (size_t)o * 1152;
  float m = 0.f;
  for (int i = tid; i < 288; i += 256) {
    const float4 v = ((const float4*)wrow)[i];
    ((float4*)wf)[i] = v;
    m = fmaxf(m, fmaxf(fmaxf(fabsf(v.x), fabsf(v.y)),
                       fmaxf(fabsf(v.z), fabsf(v.w))));
  }
  red[tid] = m;
  __syncthreads();
  for (int s = 128; s > 0; s >>= 1) {
    if (tid < s) red[tid] = fmaxf(red[tid], red[tid + s]);
    __syncthreads();
  }
  const float sc = red[0] / 127.0f;   // max/QMAX, fp32, matches reference
  if (tid == 0) alpha[o] = sc * sxp[0];
  if (tid < 72) {   // r = tid/8, c02 = (tid>>2)&1, quad = tid&3
    const int r = tid >> 3, c02 = (tid >> 2) & 1, quad = tid & 3;
    const int og = o >> 5, t = (o >> 4) & 1, l16 = o & 15;
    int4v pk;
#pragma unroll
    for (int d = 0; d < 4; ++d) {
      unsigned int p = 0;
#pragma unroll
      for (int k = 0; k < 4; ++k) {
        const int c = c02 * 64 + quad * 16 + d * 4 + k;
        const int q =
            (int)fminf(127.f, fmaxf(-127.f, rintf(wf[c * 9 + r] / sc)));
        p |= ((unsigned int)(q & 255)) << (8 * k);
      }
      pk[d] = (int)p;
    }
    *(int4v*)(qwf + (size_t)og * 36864 + ((r * 2 + c02) * 2 + t) * 1024 +
              (quad * 16 + l16) * 16) = pk;   // HW lane order (R16 fix)
  }
}

// ---------------- kernel 2: x quantization -> swizzled im2col rows ---------
// qxp byte ((b*56+h)*56 + w)*128 + j holds q(x[b][ j^(((w+1)&7)<<4) ][h][w]).
__global__ __launch_bounds__(256) void quant_x_kernel(
    const float* __restrict__ x, const float* __restrict__ sxp,
    unsigned int* __restrict__ qxp) {
  __shared__ char ldsA[128 * 60];   // [c][w] quantized bytes, stride 60
  const int row = blockIdx.x;       // b*56 + h
  const int b = row / 56, h = row % 56;
  const float sx = sxp[0];
  for (int i = threadIdx.x; i < 1792; i += 256) {
    const int c = i / 14, f = i % 14;
    const float4 v =
        *(const float4*)(x + (((size_t)b * 128 + c) * 56 + h) * 56 + 4 * f);
    unsigned int pk;
    pk  = (unsigned int)((int)fminf(127.f, fmaxf(-127.f, rintf(v.x / sx))) & 255);
    pk |= ((unsigned int)((int)fminf(127.f, fmaxf(-127.f, rintf(v.y / sx))) & 255)) << 8;
    pk |= ((unsigned int)((int)fminf(127.f, fmaxf(-127.f, rintf(v.z / sx))) & 255)) << 16;
    pk |= ((unsigned int)((int)fminf(127.f, fmaxf(-127.f, rintf(v.w / sx))) & 255)) << 24;
    *(unsigned int*)(ldsA + c * 60 + 4 * f) = pk;
  }
  __syncthreads();
  unsigned int* orow = qxp + (size_t)row * 56 * 32;
  for (int i = threadIdx.x; i < 1792; i += 256) {
    const int w = i >> 5, jd = i & 31;
    // byte p of row w holds channel p ^ (((w+1)&7)<<4); dword-level: ph<<2
    const int c0 = (jd ^ (((w + 1) & 7) << 2)) << 2;  // channel base (4-run)
    unsigned int pk = 0;
#pragma unroll
    for (int k = 0; k < 4; ++k)
      pk |= ((unsigned int)(unsigned char)ldsA[(c0 + k) * 60 + w]) << (8 * k);
    orow[i] = pk;
  }
}

// ---------------- kernel 3: conv (16x16x64 i8, 8 waves, 256 o per block) ---
#define XSLAB 8448                  // 66 cols * 128B, contiguous (no pad)

__global__ __launch_bounds__(512, 4) void conv_kernel(
    const char* __restrict__ qxp, const char* __restrict__ qwf,
    const float* __restrict__ alpha, const float* __restrict__ bias,
    float* __restrict__ out) {
  __shared__ __attribute__((aligned(16))) char Xs8[3 * XSLAB];  // 25,344 B

  // chunked XCD swizzle: 1792 = 8*224; XCD (id&7) owns bi in [xcd*224,+224)
  const int id = blockIdx.x;        // 0..1791
  const int xcd = id & 7;
  const int bi = xcd * 224 + (id >> 3);
  const int b  = bi / 56;
  const int oh = bi % 56;
  const int tid = threadIdx.x;      // 0..511
  const int wave = tid >> 6, lane = tid & 63;   // wave = og, 0..7
  const int l16 = lane & 15, quad = lane >> 4;

  // A-operand base: per-lane int4v (16B); wave chunk per (r,c02,t) = 1KB.
  const int4v* wbA = (const int4v*)(qwf + (size_t)wave * 36864) + lane;
  int4v ap[2][2][2];                // [buf][c02][t]
#pragma unroll
  for (int c02 = 0; c02 < 2; ++c02)
#pragma unroll
    for (int t = 0; t < 2; ++t)
      ap[0][c02][t] = wbA[(size_t)(c02 * 2 + t) * 64];   // r = 0

  // ---- stage 3 input rows once for ALL 256 o (512 threads) ----
  for (int kh = 0; kh < 3; ++kh) {
    const int ih = oh - 1 + kh;
    char* slab = Xs8 + kh * XSLAB;
    if (ih >= 0 && ih < HH) {
      const char* src = qxp + ((size_t)b * 56 + ih) * 7168;
      if (tid < 448) gload_lds16(src + tid * 16, slab + 128 + tid * 16);
      for (int i = tid; i < 320; i += 512) {              // zero cols 0,57..65
        const int cg = i >> 5, dw = i & 31;
        const int col = (cg == 0) ? 0 : 56 + cg;
        ((unsigned int*)slab)[col * 32 + dw] = 0u;
      }
    } else {
      for (int i = tid; i < 2112; i += 512) ((unsigned int*)slab)[i] = 0u;
    }
  }

  int4v acc[2][4];
#pragma unroll
  for (int t = 0; t < 2; ++t)
#pragma unroll
    for (int u = 0; u < 4; ++u) acc[t][u] = (int4v){0, 0, 0, 0};

  __syncthreads();   // drains vmcnt (global_load_lds + ap[0]) + lgkm

  // ---- K-loop: 18 substeps (9 taps x 2 K64-chunks), B-pp, A-pp per tap ----
  int4v bops[2][4];
  {
    const int ph0 = (l16 & 7) << 4;         // g=0: kh=0, kw=0
    const int boff0 = (quad * 16) ^ ph0;    // c02=0
#pragma unroll
    for (int u = 0; u < 4; ++u)
      bops[0][u] = *(const int4v*)(Xs8 + (u * 16 + l16) * 128 + boff0);
  }
#pragma unroll
  for (int ss = 0; ss < 18; ++ss) {
    const int g = ss >> 1, c02 = ss & 1;
    // prefetch next substep's B fragments (static after unroll)
    if (ss + 1 < 18) {
      const int gn = (ss + 1) >> 1, cn = (ss + 1) & 1;
      const int khn = gn / 3, kwn = gn % 3;
      const char* Xkn = Xs8 + khn * XSLAB;
      const int phn = ((l16 + kwn) & 7) << 4;
      const int boffn = (cn * 64 + quad * 16) ^ phn;
#pragma unroll
      for (int u = 0; u < 4; ++u)
        bops[(ss + 1) & 1][u] =
            *(const int4v*)(Xkn + (u * 16 + l16 + kwn) * 128 + boffn);
    }
    // prefetch next tap's A fragments (once per g)
    if (c02 == 0 && g < 8) {
#pragma unroll
      for (int cc = 0; cc < 2; ++cc)
#pragma unroll
        for (int t = 0; t < 2; ++t)
          ap[(g + 1) & 1][cc][t] =
              wbA[(size_t)(((g + 1) * 2 + cc) * 2 + t) * 64];
    }
#pragma unroll
    for (int u = 0; u < 4; ++u) {
      acc[0][u] = __builtin_amdgcn_mfma_i32_16x16x64_i8(
          ap[g & 1][c02][0], bops[ss & 1][u], acc[0][u], 0, 0, 0);
      acc[1][u] = __builtin_amdgcn_mfma_i32_16x16x64_i8(
          ap[g & 1][c02][1], bops[ss & 1][u], acc[1][u], 0, 0, 0);
    }
  }

  // C/D layout (HW-verified, proven since R12): row = quad*4+r, col = l16
#pragma unroll
  for (int t = 0; t < 2; ++t) {
#pragma unroll
    for (int r = 0; r < 4; ++r) {
      const int o = wave * 32 + t * 16 + quad * 4 + r;
      const float al = alpha[o], bz = bias[o];
      float* orow = out + (((size_t)b * OCH + o) * HH + oh) * WW;
#pragma unroll
      for (int u = 0; u < 4; ++u) {
        const int ow = u * 16 + l16;
        if (ow < WW) orow[ow] = (float)acc[t][u][r] * al + bz;
      }
    }
  }
}

// ---------------- fallback: R5's proven fused kernel (ws-free) -------------
#define FAS_ROW 392
#define FXS_ROW 136
#define FLDS_XS (128 * FAS_ROW)
#define FLDS_SC (FLDS_XS + 66 * FXS_ROW)
#define FLDS_AL (FLDS_SC + 512)
#define FLDS_BI (FLDS_AL + 512)
#define FLDS_RED (FLDS_BI + 512)
#define FLDS_TOT (FLDS_RED + 1024)

__global__ __launch_bounds__(256) void conv_fused_kernel(
    const float* __restrict__ x, const float* __restrict__ w,
    const float* __restrict__ bias, const float* __restrict__ sxp,
    float* __restrict__ out) {
  __shared__ __attribute__((aligned(16))) char lds[FLDS_TOT];
  char* As8 = lds;
  char* Xs8 = lds + FLDS_XS;
  float* scaleS = (float*)(lds + FLDS_SC);
  float* alphaS = (float*)(lds + FLDS_AL);
  float* biasS  = (float*)(lds + FLDS_BI);
  float* red    = (float*)(lds + FLDS_RED);

  const int bi = blockIdx.x;
  const int b  = bi / 56;
  const int oh = bi % 56;
  const int o0 = blockIdx.y * 128;
  const int tid = threadIdx.x;
  const int wave = tid >> 6, lane = tid & 63;
  const int l16 = lane & 15, quad = lane >> 4;
  const float sx = sxp[0];

  typedef __attribute__((ext_vector_type(4))) int int4vf;
  int m_r[4], n_r[4];
  {
    int4vf zz = {0, 0, 0, 0};
    long a1 = 0, b1 = 0, a2 = 0, b2 = 0;
    if (quad == 0) { a1 = 1L; b1 = (long)(l16 + 1); a2 = (long)(l16 + 1); b2 = 1L; }
    int4vf d1 = __builtin_amdgcn_mfma_i32_16x16x32_i8(a1, b1, zz, 0, 0, 0);
    int4vf d2 = __builtin_amdgcn_mfma_i32_16x16x32_i8(a2, b2, zz, 0, 0, 0);
#pragma unroll
    for (int r = 0; r < 4; ++r) { n_r[r] = (d1[r] - 1) & 15; m_r[r] = (d2[r] - 1) & 15; }
  }
  {
    const int o = tid >> 1, half = tid & 1;
    const float4* p = (const float4*)(w + (size_t)(o0 + o) * 1152 + half * 576);
    float m = 0.f;
#pragma unroll 4
    for (int i = 0; i < 144; ++i) {
      const float4 v = p[i];
      m = fmaxf(m, fmaxf(fmaxf(fabsf(v.x), fabsf(v.y)), fmaxf(fabsf(v.z), fabsf(v.w))));
    }
    red[tid] = m;
  }
  __syncthreads();
  {
    const int o = tid >> 1;
    if ((tid & 1) == 0) {
      const float sc = fmaxf(red[2 * o], red[2 * o + 1]) / 127.0f;
      scaleS[o] = sc; alphaS[o] = sc * sx; biasS[o] = bias[o0 + o];
    }
  }
  int4vf acc[2][4];
#pragma unroll
  for (int t = 0; t < 2; ++t)
#pragma unroll
    for (int u = 0; u < 4; ++u) acc[t][u] = (int4vf){0, 0, 0, 0};

  for (int kh = 0; kh < 3; ++kh) {
    const int ih = oh - 1 + kh;
    const bool row_ok = (ih >= 0) && (ih < HH);
    __syncthreads();
    for (int idx = tid; idx < 66 * 128; idx += 256) {
      const int col = idx % 66, c = idx / 66, iw = col - 1;
      int q = 0;
      if (row_ok && iw >= 0 && iw < WW) {
        const float xv = x[(((size_t)b * CIN + c) * HH + ih) * WW + iw];
        q = (int)fminf(127.f, fmaxf(-127.f, rintf(xv / sx)));
      }
      Xs8[col * FXS_ROW + c] = (char)q;
    }
    for (int idx = tid; idx < 16384; idx += 256) {
      const int c = idx & 127, o = idx >> 7;
      const float s = scaleS[o];
      const float* wp = w + (size_t)(o0 + o) * 1152 + c * 9 + kh * 3;
#pragma unroll
      for (int kw = 0; kw < 3; ++kw) {
        const int q = (int)fminf(127.f, fmaxf(-127.f, rintf(wp[kw] / s)));
        As8[o * FAS_ROW + kw * 128 + c] = (char)q;
      }
    }
    __syncthreads();
    const int obase = wave * 32;
#pragma unroll
    for (int kw = 0; kw < 3; ++kw) {
#pragma unroll
      for (int c0 = 0; c0 < 128; c0 += 32) {
        long aop[2], bop[4];
#pragma unroll
        for (int t = 0; t < 2; ++t)
          aop[t] = *(const long*)(As8 + (obase + t * 16 + l16) * FAS_ROW + kw * 128 + c0 + quad * 8);
#pragma unroll
        for (int u = 0; u < 4; ++u)
          bop[u] = *(const long*)(Xs8 + (u * 16 + l16 + kw) * FXS_ROW + c0 + quad * 8);
#pragma unroll
        for (int t = 0; t < 2; ++t)
#pragma unroll
          for (int u = 0; u < 4; ++u)
            acc[t][u] = __builtin_amdgcn_mfma_i32_16x16x32_i8(aop[t], bop[u], acc[t][u], 0, 0, 0);
      }
    }
  }
#pragma unroll
  for (int t = 0; t < 2; ++t) {
#pragma unroll
    for (int u = 0; u < 4; ++u) {
#pragma unroll
      for (int r = 0; r < 4; ++r) {
        const int ol = wave * 32 + t * 16 + m_r[r];
        const int ow = u * 16 + n_r[r];
        if (ow < WW)
          out[(((size_t)b * OCH + o0 + ol) * HH + oh) * WW + ow] =
              (float)acc[t][u][r] * alphaS[ol] + biasS[ol];
      }
    }
  }
}

extern "C" void kernel_launch(void* const* d_in, const int* in_sizes, int n_in,
                              void* d_out, int out_size, void* d_ws, size_t ws_size,
                              hipStream_t stream) {
  const float *x = nullptr, *w = nullptr, *bias = nullptr, *sx = nullptr;
  for (int i = 0; i < n_in; ++i) {
    const int s = in_sizes[i];
    if (s == BATCH * CIN * HH * WW) x = (const float*)d_in[i];
    else if (s == OCH * CIN * 9)    w = (const float*)d_in[i];
    else if (s == OCH)              bias = (const float*)d_in[i];
    else if (s == 1)                sx = (const float*)d_in[i];
  }
  if (!x || !w || !bias || !sx) {
    x = (const float*)d_in[0]; w = (const float*)d_in[1];
    bias = (const float*)d_in[2]; sx = (const float*)d_in[3];
  }
  float* out = (float*)d_out;

  if (ws_size >= (size_t)WS_NEEDED) {
    unsigned int* qxp = (unsigned int*)d_ws;
    char* qwf = (char*)d_ws + QX_BYTES;
    float* alpha = (float*)((char*)d_ws + QX_BYTES + QW_BYTES);
    quant_w_kernel<<<OCH, 256, 0, stream>>>(w, sx, qwf, alpha);
    quant_x_kernel<<<BATCH * HH, 256, 0, stream>>>(x, sx, qxp);
    conv_kernel<<<BATCH * HH, 512, 0, stream>>>(
        (const char*)qxp, qwf, alpha, bias, out);
  } else {
    conv_fused_kernel<<<dim3(BATCH * HH, 2), 256, 0, stream>>>(x, w, bias, sx, out);
  }
}